// Round 14
// baseline (158.482 us; speedup 1.0000x reference)
//
#include <hip/hip_runtime.h>
#include <math.h>

#define BB 4
#define HH 8
#define LL 2048
#define DD 64
#define SK 40            // sample_k == u == 40 for L=2048, FACTOR=5
#define BH (BB*HH)       // 32
#define NC 8             // key-chunks per (bh,u) in attn
#define CK 256           // keys per chunk (NC*CK == LL)
#define SCP (CK + 4)     // padded SCT row stride (floats); 260*4=1040B, 16B-aligned

__device__ __forceinline__ unsigned ordu(float v) {
    unsigned u = __float_as_uint(v);
    return (u & 0x80000000u) ? ~u : (u | 0x80000000u);
}

__device__ __forceinline__ float dot4(float4 a, float4 b) {
    return a.x * b.x + a.y * b.y + a.z * b.z + a.w * b.w;
}

// ---------------------------------------------------------------------------
// Stage 1 (unchanged from round 12): 512 blocks, dual-bh L2-phased gather + vsum.
__global__ __launch_bounds__(256) void stage1_kernel(
        const float* __restrict__ Q, const float* __restrict__ K,
        const float* __restrict__ V, const int* __restrict__ IDX,
        float* __restrict__ M, float* __restrict__ csum) {
    int tid = threadIdx.x;
    int b = blockIdx.x;               // [0,512)
    int bhLo = b & 7;                 // XCD affinity
    int bhA = bhLo + 8 * ((b >> 3) & 1);
    int bhB = bhA + 16;
    int chunk = b >> 4;               // [0,32)
    int qbase = chunk * 64;
    int w = tid >> 6, lane = tid & 63;
    int qw = lane >> 2, c = lane & 3;
    int qi = w * 16 + qw;
    int qpos = qbase + qi;

    __shared__ int sidx[64 * SK];     // 10 KB (shared across both bh)
    __shared__ float part[4][DD];

    for (int i = tid; i < 64 * SK; i += 256) sidx[i] = IDX[(size_t)qbase * SK + i];

    const float4* Q4 = (const float4*)Q;
    const float4* K4 = (const float4*)K;
    float4 qA[4], qB[4];
    #pragma unroll
    for (int j = 0; j < 4; ++j) {
        qA[j] = Q4[((size_t)bhA * LL + qpos) * 16 + j * 4 + c];
        qB[j] = Q4[((size_t)bhB * LL + qpos) * 16 + j * 4 + c];
    }
    __syncthreads();

    size_t kbA = (size_t)bhA * LL * 16;
    size_t kbB = (size_t)bhB * LL * 16;
    float mxA = -INFINITY, smA = 0.f, mxB = -INFINITY, smB = 0.f;

    float4 a0[4], b0[4], a1[4], b1[4];
    {
        int ks = sidx[qi * SK];
        const float4* krA = K4 + kbA + (size_t)ks * 16;
        const float4* krB = K4 + kbB + (size_t)ks * 16;
        #pragma unroll
        for (int j = 0; j < 4; ++j) { a0[j] = krA[j * 4 + c]; b0[j] = krB[j * 4 + c]; }
    }
    for (int s = 0; s < SK; s += 2) {
        {
            int ks = sidx[qi * SK + s + 1];
            const float4* krA = K4 + kbA + (size_t)ks * 16;
            const float4* krB = K4 + kbB + (size_t)ks * 16;
            #pragma unroll
            for (int j = 0; j < 4; ++j) { a1[j] = krA[j * 4 + c]; b1[j] = krB[j * 4 + c]; }
        }
        {
            float pA = dot4(qA[0], a0[0]) + dot4(qA[1], a0[1])
                     + dot4(qA[2], a0[2]) + dot4(qA[3], a0[3]);
            float pB = dot4(qB[0], b0[0]) + dot4(qB[1], b0[1])
                     + dot4(qB[2], b0[2]) + dot4(qB[3], b0[3]);
            pA += __shfl_xor(pA, 1, 64); pA += __shfl_xor(pA, 2, 64);
            pB += __shfl_xor(pB, 1, 64); pB += __shfl_xor(pB, 2, 64);
            mxA = fmaxf(mxA, pA); smA += pA;
            mxB = fmaxf(mxB, pB); smB += pB;
        }
        if (s + 2 < SK) {
            int ks = sidx[qi * SK + s + 2];
            const float4* krA = K4 + kbA + (size_t)ks * 16;
            const float4* krB = K4 + kbB + (size_t)ks * 16;
            #pragma unroll
            for (int j = 0; j < 4; ++j) { a0[j] = krA[j * 4 + c]; b0[j] = krB[j * 4 + c]; }
        }
        {
            float pA = dot4(qA[0], a1[0]) + dot4(qA[1], a1[1])
                     + dot4(qA[2], a1[2]) + dot4(qA[3], a1[3]);
            float pB = dot4(qB[0], b1[0]) + dot4(qB[1], b1[1])
                     + dot4(qB[2], b1[2]) + dot4(qB[3], b1[3]);
            pA += __shfl_xor(pA, 1, 64); pA += __shfl_xor(pA, 2, 64);
            pB += __shfl_xor(pB, 1, 64); pB += __shfl_xor(pB, 2, 64);
            mxA = fmaxf(mxA, pA); smA += pA;
            mxB = fmaxf(mxB, pB); smB += pB;
        }
    }
    if (c == 0) {
        M[(size_t)bhA * LL + qpos] = mxA - smA * (1.0f / (float)LL);
        M[(size_t)bhB * LL + qpos] = mxB - smB * (1.0f / (float)LL);
    }

    {
        int bhv = (b & 7) + 8 * ((b >> 3) & 3);
        int cv = b >> 5;
        int d = tid & 63, sg = tid >> 6;
        size_t base = (size_t)bhv * LL * DD;
        int row0 = cv * 128 + sg * 32;
        float s2 = 0.f;
        for (int j = 0; j < 32; ++j) s2 += V[base + (size_t)(row0 + j) * DD + d];
        part[sg][d] = s2;
        __syncthreads();
        if (sg == 0)
            csum[((size_t)bhv * 16 + cv) * DD + d] =
                part[0][d] + part[1][d] + part[2][d] + part[3][d];
    }
}

// ---------------------------------------------------------------------------
// radix top-40 of M (unchanged). 32 blocks.
__global__ __launch_bounds__(256) void radix_kernel(
        const float* __restrict__ M, int* __restrict__ topk) {
    int tid = threadIdx.x;
    int bh = blockIdx.x;
    __shared__ unsigned hist[256];
    __shared__ unsigned sfx[256];
    __shared__ unsigned bc_prefix, bc_need;
    __shared__ unsigned cnt_gt, cnt_eq;
    __shared__ int eqlist[128];

    unsigned v[8];
    #pragma unroll
    for (int j = 0; j < 8; ++j)
        v[j] = ordu(M[(size_t)bh * LL + tid + j * 256]);

    unsigned prefix = 0, need = SK;
    #pragma unroll
    for (int pass = 0; pass < 4; ++pass) {
        const int s = 24 - 8 * pass;
        const unsigned maskHigh = (pass == 0) ? 0u : (0xFFFFFFFFu << (s + 8));
        hist[tid] = 0;
        __syncthreads();
        #pragma unroll
        for (int j = 0; j < 8; ++j)
            if (((v[j] ^ prefix) & maskHigh) == 0)
                atomicAdd(&hist[(v[j] >> s) & 0xFF], 1u);
        __syncthreads();
        sfx[tid] = hist[tid];
        __syncthreads();
        #pragma unroll
        for (int off = 1; off < 256; off <<= 1) {
            unsigned t = (tid + off < 256) ? sfx[tid + off] : 0u;
            __syncthreads();
            sfx[tid] += t;
            __syncthreads();
        }
        unsigned above = (tid < 255) ? sfx[tid + 1] : 0u;
        if (above < need && sfx[tid] >= need) {
            bc_prefix = prefix | ((unsigned)tid << s);
            bc_need = need - above;
        }
        __syncthreads();
        prefix = bc_prefix;
        need = bc_need;
        __syncthreads();
    }
    unsigned T = prefix;
    if (tid == 0) { cnt_gt = 0; cnt_eq = 0; }
    __syncthreads();
    #pragma unroll
    for (int j = 0; j < 8; ++j) {
        int idx = tid + j * 256;
        if (v[j] > T) { unsigned p = atomicAdd(&cnt_gt, 1u); topk[bh * SK + p] = idx; }
        else if (v[j] == T) { unsigned p = atomicAdd(&cnt_eq, 1u); if (p < 128) eqlist[p] = idx; }
    }
    __syncthreads();
    if (tid == 0) {
        int ne = (int)min(cnt_eq, 128u);
        unsigned base = cnt_gt;
        for (unsigned r2 = 0; r2 < need; ++r2) {
            int bj = 0, bv = 0x7FFFFFFF;
            for (int j = 0; j < ne; ++j)
                if (eqlist[j] < bv) { bv = eqlist[j]; bj = j; }
            topk[bh * SK + base + r2] = bv;
            eqlist[bj] = 0x7FFFFFFF;
        }
    }
}

// ---------------------------------------------------------------------------
// Fused attn + cumsum. Blocks [0,256): attn chunks of CK=256 keys, 2 keys per
// thread-pair (Q LDS reads amortized 2x), transposed SCT[u][k] so Phase B/C
// use b128 LDS reads. Blocks [256,768): V cumsum -> out. 3 blocks/CU.
__global__ __launch_bounds__(256, 3) void attn_cumsum_kernel(
        const float* __restrict__ Q, const float* __restrict__ K,
        const float* __restrict__ V, const int* __restrict__ topk,
        const float* __restrict__ csum, float* __restrict__ out,
        float* __restrict__ pm, float* __restrict__ pl,
        float* __restrict__ po) {
    int tid = threadIdx.x;
    __shared__ int qp[SK];
    __shared__ float4 sq4[SK][16];      // 10 KB
    __shared__ float SCT[SK][SCP];      // 40x260 floats = 41.6 KB
    __shared__ float part[4][DD];       // 1 KB (cumsum)

    if (blockIdx.x < 256) {
        // ================= attn chunk =================
        int x = blockIdx.x;
        int bhLo = x & 7;                 // XCD affinity
        int r = x >> 3;                   // [0,32)
        int c = r & 7;                    // chunk [0,NC)
        int bhHi = r >> 3;                // [0,4)
        int bh = bhHi * 8 + bhLo;
        int w = tid >> 6, lane = tid & 63;
        int cbase = c * CK;

        if (tid < SK) qp[tid] = topk[bh * SK + tid];
        __syncthreads();
        const float4* Q4 = (const float4*)Q;
        const float4* K4 = (const float4*)K;
        const float4* V4 = (const float4*)V;
        for (int i = tid; i < SK * 16; i += 256) {
            int u = i >> 4, j = i & 15;
            sq4[u][j] = Q4[((size_t)bh * LL + qp[u]) * 16 + j];
        }
        __syncthreads();

        // ---- Phase A: scores. thread-pair = (kk, half); 2 keys per pair.
        {
            int half = tid & 1;
            int kk = tid >> 1;            // [0,128): keys kk and kk+128
            int kg1 = cbase + kk;
            int kg2 = cbase + kk + 128;
            size_t kb4 = (size_t)bh * LL * 16;
            float4 k1[8], k2[8];
            const float4* kr1 = K4 + kb4 + (size_t)kg1 * 16 + half * 8;
            const float4* kr2 = K4 + kb4 + (size_t)kg2 * 16 + half * 8;
            #pragma unroll
            for (int j = 0; j < 8; ++j) { k1[j] = kr1[j]; k2[j] = kr2[j]; }
            #pragma unroll 4
            for (int u = 0; u < SK; ++u) {
                int qpu = qp[u];
                if (cbase > qpu) {        // whole chunk masked for this u
                    if (half == 0) { SCT[u][kk] = -INFINITY; SCT[u][kk + 128] = -INFINITY; }
                    continue;
                }
                float p1 = 0.f, p2 = 0.f;
                #pragma unroll
                for (int j = 0; j < 8; ++j) {
                    float4 qv = sq4[u][half * 8 + j];
                    p1 += dot4(k1[j], qv);
                    p2 += dot4(k2[j], qv);
                }
                p1 += __shfl_xor(p1, 1, 64);
                p2 += __shfl_xor(p2, 1, 64);
                if (half == 0) {
                    SCT[u][kk]       = (kg1 <= qpu) ? p1 * 0.125f : -INFINITY;
                    SCT[u][kk + 128] = (kg2 <= qpu) ? p2 * 0.125f : -INFINITY;
                }
            }
        }
        __syncthreads();

        // ---- Phase B: per-u chunk max + exp + sumexp. Wave w owns u in
        // [w*10, w*10+10); lane reads SCT[u][4*lane..+4) as b128.
        for (int ui = 0; ui < 10; ++ui) {
            int u = w * 10 + ui;
            float4 sv = *(const float4*)&SCT[u][lane * 4];
            float m = fmaxf(fmaxf(sv.x, sv.y), fmaxf(sv.z, sv.w));
            #pragma unroll
            for (int off = 32; off > 0; off >>= 1) m = fmaxf(m, __shfl_xor(m, off, 64));
            float4 ev = make_float4(0.f, 0.f, 0.f, 0.f);
            if (m != -INFINITY) {
                ev.x = expf(sv.x - m); ev.y = expf(sv.y - m);
                ev.z = expf(sv.z - m); ev.w = expf(sv.w - m);
            }
            *(float4*)&SCT[u][lane * 4] = ev;
            float ls = ev.x + ev.y + ev.z + ev.w;
            #pragma unroll
            for (int off = 32; off > 0; off >>= 1) ls += __shfl_xor(ls, off, 64);
            if (lane == 0) {
                size_t pb = (size_t)(bh * SK + u) * NC + c;
                pm[pb] = m;
                pl[pb] = ls;
            }
        }
        __syncthreads();

        // ---- Phase C: PV = P(40xCK) x V(CKx64). thread = (ks, dg, ug);
        // per t-iter: b128 SCT read covers 4 keys -> 4 V rows, 16 fma4/u.
        {
            int ks = tid & 3;
            int dg = (tid >> 2) & 15;
            int ug = tid >> 6;            // == w
            int u0 = ug * 10;
            float4 acc[10];
            #pragma unroll
            for (int i = 0; i < 10; ++i) acc[i] = make_float4(0.f, 0.f, 0.f, 0.f);
            for (int t = 0; t < CK / 16; ++t) {
                int k0 = t * 16 + ks * 4;
                float4 vv0 = V4[((size_t)bh * LL + cbase + k0 + 0) * 16 + dg];
                float4 vv1 = V4[((size_t)bh * LL + cbase + k0 + 1) * 16 + dg];
                float4 vv2 = V4[((size_t)bh * LL + cbase + k0 + 2) * 16 + dg];
                float4 vv3 = V4[((size_t)bh * LL + cbase + k0 + 3) * 16 + dg];
                #pragma unroll
                for (int i = 0; i < 10; ++i) {
                    float4 pw = *(const float4*)&SCT[u0 + i][k0];
                    acc[i].x += pw.x * vv0.x + pw.y * vv1.x + pw.z * vv2.x + pw.w * vv3.x;
                    acc[i].y += pw.x * vv0.y + pw.y * vv1.y + pw.z * vv2.y + pw.w * vv3.y;
                    acc[i].z += pw.x * vv0.z + pw.y * vv1.z + pw.z * vv2.z + pw.w * vv3.z;
                    acc[i].w += pw.x * vv0.w + pw.y * vv1.w + pw.z * vv2.w + pw.w * vv3.w;
                }
            }
            #pragma unroll
            for (int i = 0; i < 10; ++i) {
                acc[i].x += __shfl_xor(acc[i].x, 1, 64); acc[i].x += __shfl_xor(acc[i].x, 2, 64);
                acc[i].y += __shfl_xor(acc[i].y, 1, 64); acc[i].y += __shfl_xor(acc[i].y, 2, 64);
                acc[i].z += __shfl_xor(acc[i].z, 1, 64); acc[i].z += __shfl_xor(acc[i].z, 2, 64);
                acc[i].w += __shfl_xor(acc[i].w, 1, 64); acc[i].w += __shfl_xor(acc[i].w, 2, 64);
            }
            if (ks == 0) {
                #pragma unroll
                for (int i = 0; i < 10; ++i) {
                    float4* dst = (float4*)&po[((size_t)(bh * SK + u0 + i) * NC + c) * DD + dg * 4];
                    *dst = acc[i];
                }
            }
        }
    } else {
        // ================= cumsum chunk =================
        int x = blockIdx.x - 256;         // [0,512)
        int bhLo = x & 7, r = x >> 3;
        int bhHi = r & 3, c = r >> 2;
        int bh = bhHi * 8 + bhLo;
        int d = tid & 63, sg = tid >> 6;
        size_t base = (size_t)bh * LL * DD;
        int row0 = c * 128 + sg * 32;
        float v[32];
        #pragma unroll
        for (int j = 0; j < 32; ++j) v[j] = V[base + (size_t)(row0 + j) * DD + d];
        float s = 0.f;
        #pragma unroll
        for (int j = 0; j < 32; ++j) s += v[j];
        part[sg][d] = s;
        __syncthreads();
        float pre = 0.f;
        for (int cc = 0; cc < c; ++cc) pre += csum[((size_t)bh * 16 + cc) * DD + d];
        for (int ss = 0; ss < sg; ++ss) pre += part[ss][d];
        float acc = pre;
        #pragma unroll
        for (int j = 0; j < 32; ++j) {
            acc += v[j];
            out[base + (size_t)(row0 + j) * DD + d] = acc;
        }
    }
}

// ---------------------------------------------------------------------------
// combine: merge NC=8 partials per (bh,u). One wave per group; 4 groups/block.
__global__ __launch_bounds__(256) void combine_kernel(
        const float* __restrict__ pm, const float* __restrict__ pl,
        const float* __restrict__ po, const int* __restrict__ topk,
        float* __restrict__ out) {
    int g = blockIdx.x * 4 + (threadIdx.x >> 6);   // [0, 1280)
    int d = threadIdx.x & 63;
    int qpos = topk[g];
    int bh = g / SK;
    size_t gb = (size_t)g * NC;
    float gm = -INFINITY;
    #pragma unroll
    for (int j = 0; j < NC; ++j) gm = fmaxf(gm, pm[gb + j]);
    float L = 0.f, o = 0.f;
    #pragma unroll
    for (int j = 0; j < NC; ++j) {
        float pmj = pm[gb + j];
        float wj = (pmj == -INFINITY) ? 0.f : expf(pmj - gm);
        L += pl[gb + j] * wj;
        o += po[(gb + j) * DD + d] * wj;
    }
    out[((size_t)bh * LL + qpos) * DD + d] = o / L;
}

// ---------------------------------------------------------------------------
extern "C" void kernel_launch(void* const* d_in, const int* in_sizes, int n_in,
                              void* d_out, int out_size, void* d_ws, size_t ws_size,
                              hipStream_t stream) {
    const float* Q   = (const float*)d_in[0];
    const float* K   = (const float*)d_in[1];
    const float* V   = (const float*)d_in[2];
    const int*   IDX = (const int*)d_in[3];
    float* out = (float*)d_out;

    char* ws = (char*)d_ws;
    float* M    = (float*)ws;  ws += (size_t)BH * LL * sizeof(float);                 // 256 KB
    int*   topk = (int*)ws;    ws += ((size_t)BH * SK * sizeof(int) + 255) & ~255ull;
    float* csum = (float*)ws;  ws += (size_t)BH * 16 * DD * sizeof(float);            // 128 KB
    float* pm   = (float*)ws;  ws += ((size_t)BH * SK * NC * sizeof(float) + 255) & ~255ull;
    float* pl   = (float*)ws;  ws += ((size_t)BH * SK * NC * sizeof(float) + 255) & ~255ull;
    float* po   = (float*)ws;  // BH*SK*NC*DD floats = 2.62 MB

    stage1_kernel<<<512, 256, 0, stream>>>(Q, K, V, IDX, M, csum);
    radix_kernel<<<32, 256, 0, stream>>>(M, topk);
    attn_cumsum_kernel<<<768, 256, 0, stream>>>(Q, K, V, topk, csum, out, pm, pl, po);
    combine_kernel<<<320, 256, 0, stream>>>(pm, pl, po, topk, out);
}